// Round 10
// baseline (4039.272 us; speedup 1.0000x reference)
//
#include <hip/hip_runtime.h>
#include <math.h>

namespace {
constexpr int kBL = 16 * 2048;
constexpr int kH = 256;
constexpr int kNOut = 12;
constexpr int kRows = 64;        // rows per block
constexpr int kThreads = 1024;   // 16 waves: 0-7 MFMA-role, 8-15 gate-role
constexpr int kS = 264;          // A row stride in shorts
constexpr int kGS = 36;          // ghb row stride in floats (2-way max on writes)
constexpr int kWhh = 3 * kH * kH;
}

using short8 = __attribute__((ext_vector_type(8))) short;
using f32x4 = __attribute__((ext_vector_type(4))) float;

__device__ inline void bsplit(float v, short& h, short& l) {
  unsigned u = __float_as_uint(v);
  unsigned rh = u + 0x7FFFu + ((u >> 16) & 1u);   // RNE to bf16
  h = (short)(rh >> 16);
  float hf = __uint_as_float(rh & 0xFFFF0000u);
  float r = v - hf;                                // exact residual
  unsigned u2 = __float_as_uint(r);
  unsigned rl = u2 + 0x7FFFu + ((u2 >> 16) & 1u);
  l = (short)(rl >> 16);
}

// split w_hh [768][256] fp32 -> bf16 hi/lo planes in d_ws
__global__ void split_whh_kernel(const float* __restrict__ w,
                                 short* __restrict__ hi, short* __restrict__ lo) {
  const int i = (blockIdx.x * 256 + threadIdx.x) * 4;
  const float4 v = *reinterpret_cast<const float4*>(w + i);
  short4 h4, l4;
  bsplit(v.x, h4.x, l4.x);
  bsplit(v.y, h4.y, l4.y);
  bsplit(v.z, h4.z, l4.z);
  bsplit(v.w, h4.w, l4.w);
  *reinterpret_cast<short4*>(hi + i) = h4;
  *reinterpret_cast<short4*>(lo + i) = l4;
}

#define MFMA(A, B, C) __builtin_amdgcn_mfma_f32_16x16x32_bf16((A), (B), (C), 0, 0, 0)

// ---- phase macros: ALL register-array indices are parse-time literals ----
#define MFMA_CHUNK(P)                                                          \
  {                                                                            \
    f32x4 a0 = {0.f, 0.f, 0.f, 0.f}, a1 = a0, a2 = a0;                         \
    const short* __restrict__ bp_h =                                           \
        Bh + ((size_t)((P) * 32 + u16 * 16 + c16)) * kH;                       \
    const short* __restrict__ bp_l =                                           \
        Bl + ((size_t)((P) * 32 + u16 * 16 + c16)) * kH;                       \
    __builtin_amdgcn_s_setprio(1);                                             \
    _Pragma("unroll") for (int kc = 0; kc < 8; ++kc) {                         \
      const int ko = kc * 32 + grp * 8;                                        \
      const short8 ah = *reinterpret_cast<const short8*>(&Ah[rt * 16 + c16][ko]); \
      const short8 al = *reinterpret_cast<const short8*>(&Al[rt * 16 + c16][ko]); \
      const short8 bh0 = *reinterpret_cast<const short8*>(bp_h + ko);          \
      const short8 bh1 = *reinterpret_cast<const short8*>(bp_h + 256 * kH + ko); \
      const short8 bh2 = *reinterpret_cast<const short8*>(bp_h + 512 * kH + ko); \
      const short8 bl0 = *reinterpret_cast<const short8*>(bp_l + ko);          \
      const short8 bl1 = *reinterpret_cast<const short8*>(bp_l + 256 * kH + ko); \
      const short8 bl2 = *reinterpret_cast<const short8*>(bp_l + 512 * kH + ko); \
      a0 = MFMA(ah, bh0, a0); a1 = MFMA(ah, bh1, a1); a2 = MFMA(ah, bh2, a2);  \
      a0 = MFMA(al, bh0, a0); a1 = MFMA(al, bh1, a1); a2 = MFMA(al, bh2, a2);  \
      a0 = MFMA(ah, bl0, a0); a1 = MFMA(ah, bl1, a1); a2 = MFMA(ah, bl2, a2);  \
    }                                                                          \
    __builtin_amdgcn_s_setprio(0);                                             \
    const int urow = u16 * 16 + c16;                                           \
    _Pragma("unroll") for (int r2 = 0; r2 < 4; ++r2) {                         \
      const int mrow = rt * 16 + grp * 4 + r2;                                 \
      ghb[(P) & 1][0][mrow][urow] = a0[r2];                                    \
      ghb[(P) & 1][1][mrow][urow] = a1[r2];                                    \
      ghb[(P) & 1][2][mrow][urow] = a2[r2];                                    \
    }                                                                          \
  }

#define GATE_CHUNK(C)                                                          \
  {                                                                            \
    if ((C) == 0) xrow = xq[grow];                                             \
    const f32x4 ev = *reinterpret_cast<const f32x4*>(                          \
        emb + (size_t)(row0 + grow) * kH + (C) * 32 + sub * 4);                \
    const f32x4 g0 = *reinterpret_cast<const f32x4*>(&ghb[(C) & 1][0][grow][sub * 4]); \
    const f32x4 g1 = *reinterpret_cast<const f32x4*>(&ghb[(C) & 1][1][grow][sub * 4]); \
    const f32x4 g2 = *reinterpret_cast<const f32x4*>(&ghb[(C) & 1][2][grow][sub * 4]); \
    const int jb = (C) * 32 + sub * 4;                                         \
    const f32x4 p0 = *reinterpret_cast<const f32x4*>(&prm[0][jb]);             \
    const f32x4 p1 = *reinterpret_cast<const f32x4*>(&prm[1][jb]);             \
    const f32x4 p2 = *reinterpret_cast<const f32x4*>(&prm[2][jb]);             \
    const f32x4 p3 = *reinterpret_cast<const f32x4*>(&prm[3][jb]);             \
    const f32x4 p4 = *reinterpret_cast<const f32x4*>(&prm[4][jb]);             \
    const f32x4 p5 = *reinterpret_cast<const f32x4*>(&prm[5][jb]);             \
    const f32x4 p6 = *reinterpret_cast<const f32x4*>(&prm[6][jb]);             \
    const f32x4 p7 = *reinterpret_cast<const f32x4*>(&prm[7][jb]);             \
    f32x4 hc = h4[(C)];                                                        \
    _Pragma("unroll") for (int i = 0; i < 4; ++i) {                            \
      const float gr = fmaf(xrow, p0[i], p3[i]) + g0[i];                       \
      const float gz = fmaf(xrow, p1[i], p4[i]) + g1[i];                       \
      const float gni = fmaf(xrow, p2[i], p5[i]);                              \
      const float rg = 1.0f / (1.0f + __expf(-gr));                            \
      const float zg = 1.0f / (1.0f + __expf(-gz));                            \
      const float ta = gni + rg * (g2[i] + p6[i]);                             \
      const float at = fabsf(ta);                                              \
      const float et = __expf(-2.0f * at);                                     \
      const float th = copysignf((1.0f - et) / (1.0f + et), ta);               \
      const float hn = fmaf(zg, hc[i] - th, th);     /* (1-z)*n + z*h_in */    \
      opart = fmaf(hn, p7[i], opart);                                          \
      hc[i] = hn + ev[i];                            /* next h_in, exact */    \
    }                                                                          \
    h4[(C)] = hc;                                                              \
  }

#define FINALIZE(STEP)                                                         \
  {                                                                            \
    float o = opart;                                                           \
    o += __shfl_xor(o, 1, 8);                                                  \
    o += __shfl_xor(o, 2, 8);                                                  \
    o += __shfl_xor(o, 4, 8);                                                  \
    o += bo;                                                                   \
    const float q = o > 0.0f ? 1.0f : -1.0f;                                   \
    if (sub == 0) {                                                            \
      const size_t gr = (size_t)(row0 + grow);                                 \
      out[gr * kNOut + (STEP)] = o;                                            \
      out[q_off + gr * kNOut + (STEP)] = q;                                    \
      xq[grow] = q;                                                            \
    }                                                                          \
    opart = 0.0f;                                                              \
    if ((STEP) < kNOut - 1) {                                                  \
      _Pragma("unroll") for (int c = 0; c < 8; ++c) {                          \
        short4 hi4, lo4;                                                       \
        bsplit(h4[c][0], hi4.x, lo4.x);                                        \
        bsplit(h4[c][1], hi4.y, lo4.y);                                        \
        bsplit(h4[c][2], hi4.z, lo4.z);                                        \
        bsplit(h4[c][3], hi4.w, lo4.w);                                        \
        *reinterpret_cast<short4*>(&Ah[grow][c * 32 + sub * 4]) = hi4;         \
        *reinterpret_cast<short4*>(&Al[grow][c * 32 + sub * 4]) = lo4;         \
      }                                                                        \
    }                                                                          \
  }

__global__ __launch_bounds__(kThreads)
void rbq_ws2_kernel(const float* __restrict__ emb,    // [BL][256]
                    const float* __restrict__ w_ih,   // [768]
                    const float* __restrict__ b_ih,   // [768]
                    const float* __restrict__ b_hh,   // [768]
                    const float* __restrict__ w_out,  // [256]
                    const float* __restrict__ b_out,  // [1]
                    const short* __restrict__ Bh,     // [768][256] bf16 hi
                    const short* __restrict__ Bl,     // [768][256] bf16 lo
                    float* __restrict__ out) {        // [2][BL][12]
  __shared__ short Ah[kRows][kS];            // h_in hi (single buffer)
  __shared__ short Al[kRows][kS];            // h_in lo
  __shared__ float ghb[2][3][kRows][kGS];    // gh chunk double-buffer
  __shared__ float prm[8][kH];               // SoA params (bank-perfect f32x4)
  __shared__ float xq[kRows];                // quantized feedback

  const int tid = threadIdx.x;
  const int lane = tid & 63;
  const int wv = __builtin_amdgcn_readfirstlane(tid >> 6);  // 0..15
  const int row0 = blockIdx.x * kRows;
  const size_t q_off = (size_t)kBL * kNOut;
  const float bo = b_out[0];

  // MFMA-role coords (waves 0..7): 16 rows (rt) x 16 units (u16) x 3 gates
  const int grp = lane >> 4;
  const int c16 = lane & 15;
  const int rt = wv & 3;
  const int u16 = (wv >> 2) & 1;

  // gate-role coords (waves 8..15): 1 row x 4 units per chunk
  const int grow = ((wv - 8) << 3) | (lane >> 3);  // 0..63
  const int sub = lane & 7;                        // 0..7

  if (tid < kH) {  // params -> LDS (SoA)
    const int u = tid;
    prm[0][u] = w_ih[u];
    prm[1][u] = w_ih[kH + u];
    prm[2][u] = w_ih[2 * kH + u];
    prm[3][u] = b_ih[u] + b_hh[u];
    prm[4][u] = b_ih[kH + u] + b_hh[kH + u];
    prm[5][u] = b_ih[2 * kH + u];
    prm[6][u] = b_hh[2 * kH + u];
    prm[7][u] = w_out[u];
  }

  f32x4 h4[8];         // gate-role: exact h_in (constant-indexed ONLY)
  float opart = 0.0f;
  float xrow = 0.0f;

  if (wv >= 8) {   // h0 = 0 -> h_in = e; write A(0); xq = 0
#pragma unroll
    for (int c = 0; c < 8; ++c) {
      const f32x4 ev = *reinterpret_cast<const f32x4*>(
          emb + (size_t)(row0 + grow) * kH + c * 32 + sub * 4);
      h4[c] = ev;
      short4 hi4, lo4;
      bsplit(ev[0], hi4.x, lo4.x);
      bsplit(ev[1], hi4.y, lo4.y);
      bsplit(ev[2], hi4.z, lo4.z);
      bsplit(ev[3], hi4.w, lo4.w);
      *reinterpret_cast<short4*>(&Ah[grow][c * 32 + sub * 4]) = hi4;
      *reinterpret_cast<short4*>(&Al[grow][c * 32 + sub * 4]) = lo4;
    }
    if (sub == 0) xq[grow] = 0.0f;
  }
  __syncthreads();

  for (int step = 0; step < kNOut; ++step) {
    if (wv < 8) { MFMA_CHUNK(0) }
    __syncthreads();
    if (wv < 8) { MFMA_CHUNK(1) } else { GATE_CHUNK(0) }
    __syncthreads();
    if (wv < 8) { MFMA_CHUNK(2) } else { GATE_CHUNK(1) }
    __syncthreads();
    if (wv < 8) { MFMA_CHUNK(3) } else { GATE_CHUNK(2) }
    __syncthreads();
    if (wv < 8) { MFMA_CHUNK(4) } else { GATE_CHUNK(3) }
    __syncthreads();
    if (wv < 8) { MFMA_CHUNK(5) } else { GATE_CHUNK(4) }
    __syncthreads();
    if (wv < 8) { MFMA_CHUNK(6) } else { GATE_CHUNK(5) }
    __syncthreads();
    if (wv < 8) { MFMA_CHUNK(7) } else { GATE_CHUNK(6) }
    __syncthreads();
    if (wv >= 8) { GATE_CHUNK(7) FINALIZE(step) }
    __syncthreads();
  }
}

extern "C" void kernel_launch(void* const* d_in, const int* in_sizes, int n_in,
                              void* d_out, int out_size, void* d_ws, size_t ws_size,
                              hipStream_t stream) {
  (void)in_sizes; (void)n_in; (void)out_size; (void)ws_size;
  const float* emb = (const float*)d_in[0];
  const float* w_ih = (const float*)d_in[1];
  const float* w_hh = (const float*)d_in[2];
  const float* b_ih = (const float*)d_in[3];
  const float* b_hh = (const float*)d_in[4];
  const float* w_out = (const float*)d_in[5];
  const float* b_out = (const float*)d_in[6];

  short* Bh = (short*)d_ws;                  // [768][256] bf16 hi
  short* Bl = Bh + kWhh;                     // [768][256] bf16 lo (768 KiB total)

  split_whh_kernel<<<kWhh / (256 * 4), 256, 0, stream>>>(w_hh, Bh, Bl);
  rbq_ws2_kernel<<<kBL / kRows, kThreads, 0, stream>>>(
      emb, w_ih, b_ih, b_hh, w_out, b_out, Bh, Bl, (float*)d_out);
}

// Round 11
// 1372.840 us; speedup vs baseline: 2.9423x; 2.9423x over previous
//
#include <hip/hip_runtime.h>
#include <math.h>

namespace {
constexpr int kBL = 16 * 2048;
constexpr int kH = 256;
constexpr int kNOut = 12;
constexpr int kThreads = 1024;   // 16 waves: 0-7 = group 0, 8-15 = group 1
constexpr int kS = 264;          // A row stride in shorts
constexpr int kWhh = 3 * kH * kH;
}

using short8 = __attribute__((ext_vector_type(8))) short;
using f32x4 = __attribute__((ext_vector_type(4))) float;

__device__ inline void bsplit(float v, short& h, short& l) {
  unsigned u = __float_as_uint(v);
  unsigned rh = u + 0x7FFFu + ((u >> 16) & 1u);   // RNE to bf16
  h = (short)(rh >> 16);
  float hf = __uint_as_float(rh & 0xFFFF0000u);
  float r = v - hf;                                // exact residual
  unsigned u2 = __float_as_uint(r);
  unsigned rl = u2 + 0x7FFFu + ((u2 >> 16) & 1u);
  l = (short)(rl >> 16);
}

// split w_hh [768][256] fp32 -> bf16 hi/lo planes in d_ws
__global__ void split_whh_kernel(const float* __restrict__ w,
                                 short* __restrict__ hi, short* __restrict__ lo) {
  const int i = (blockIdx.x * 256 + threadIdx.x) * 4;
  const float4 v = *reinterpret_cast<const float4*>(w + i);
  short4 h4, l4;
  bsplit(v.x, h4.x, l4.x);
  bsplit(v.y, h4.y, l4.y);
  bsplit(v.z, h4.z, l4.z);
  bsplit(v.w, h4.w, l4.w);
  *reinterpret_cast<short4*>(hi + i) = h4;
  *reinterpret_cast<short4*>(lo + i) = l4;
}

#define MFMA(A, B, C) __builtin_amdgcn_mfma_f32_16x16x32_bf16((A), (B), (C), 0, 0, 0)

// (1024, 4): the r4-proven envelope -> 128 unified regs/wave (64 arch + 64 acc).
__global__ __launch_bounds__(kThreads, 4)
void rbq_pp_kernel(const float* __restrict__ emb,    // [BL][256]
                   const float* __restrict__ w_ih,   // [768]
                   const float* __restrict__ b_ih,   // [768]
                   const float* __restrict__ b_hh,   // [768]
                   const float* __restrict__ w_out,  // [256]
                   const float* __restrict__ b_out,  // [1]
                   const short* __restrict__ Bh,     // [768][256] bf16 hi
                   const short* __restrict__ Bl,     // [768][256] bf16 lo
                   float* __restrict__ out) {        // [2][BL][12]
  __shared__ short Ah[2][32][kS];    // per-group h_in hi
  __shared__ short Al[2][32][kS];    // per-group h_in lo
  __shared__ float prm[10][kH];      // wir,wiz,win, bir,biz,bin, bhr,bhz,bhn, wo
  __shared__ float osc[2][32][12];   // per-group o partials (stride 12: aligned)

  const int tid = threadIdx.x;
  const int lane = tid & 63;
  const int wv = __builtin_amdgcn_readfirstlane(tid >> 6);  // 0..15
  const int gid = wv >> 3;           // group: 0 or 1 (wave-uniform)
  const int gwv = wv & 7;            // wave within group: owns H-units gwv*32..+31
  const int grp = lane >> 4;
  const int c16 = lane & 15;
  const int row0 = blockIdx.x * 64 + gid * 32;   // group's first global row
  const size_t q_off = (size_t)kBL * kNOut;
  const float bo = b_out[0];

  if (tid < kH) {
    const int u = tid;
    prm[0][u] = w_ih[u];
    prm[1][u] = w_ih[kH + u];
    prm[2][u] = w_ih[2 * kH + u];
    prm[3][u] = b_ih[u];
    prm[4][u] = b_ih[kH + u];
    prm[5][u] = b_ih[2 * kH + u];
    prm[6][u] = b_hh[u];
    prm[7][u] = b_hh[kH + u];
    prm[8][u] = b_hh[2 * kH + u];
    prm[9][u] = w_out[u];
  }

  // init: h0 = 0 -> h_in = e (exact, in regs); split copy into group's A
  float h_reg[2][4][2];
  float xqr = 0.0f;                  // q feedback for local row == lane (<32)
#pragma unroll
  for (int m = 0; m < 2; ++m)
#pragma unroll
    for (int r = 0; r < 4; ++r)
#pragma unroll
      for (int t = 0; t < 2; ++t) {
        const int rl = m * 16 + grp * 4 + r;
        const int j = gwv * 32 + t * 16 + c16;
        const float e = emb[(size_t)(row0 + rl) * kH + j];
        h_reg[m][r][t] = e;
        short hh, hl;
        bsplit(e, hh, hl);
        Ah[gid][rl][j] = hh;
        Al[gid][rl][j] = hl;
      }
  __syncthreads();

  f32x4 acc[2][2][3];   // lives M-phase -> consumed next G-phase (same wave)

  // ---- MFMA phase: gh for group's 32 rows, this wave's 32 units x 3 gates ----
  auto mfma_phase = [&]() {
#pragma unroll
    for (int t = 0; t < 2; ++t) {
      const int j = gwv * 32 + t * 16 + c16;
      const float br_ = prm[6][j], bz_ = prm[7][j], bn_ = prm[8][j];
#pragma unroll
      for (int m = 0; m < 2; ++m) {
        acc[m][t][0] = f32x4{br_, br_, br_, br_};
        acc[m][t][1] = f32x4{bz_, bz_, bz_, bz_};
        acc[m][t][2] = f32x4{bn_, bn_, bn_, bn_};
      }
    }
    __builtin_amdgcn_s_setprio(1);
#pragma unroll 1
    for (int kc = 0; kc < 8; ++kc) {
      const int ko = kc * 32 + grp * 8;
      const short8 ah0 = *reinterpret_cast<const short8*>(&Ah[gid][c16][ko]);
      const short8 al0 = *reinterpret_cast<const short8*>(&Al[gid][c16][ko]);
      const short8 ah1 = *reinterpret_cast<const short8*>(&Ah[gid][16 + c16][ko]);
      const short8 al1 = *reinterpret_cast<const short8*>(&Al[gid][16 + c16][ko]);
#pragma unroll
      for (int t = 0; t < 2; ++t) {
        const int j = gwv * 32 + t * 16 + c16;
        short8 bh[3], bl[3];
#pragma unroll
        for (int g = 0; g < 3; ++g) {
          const size_t base = (size_t)(g * kH + j) * kH + ko;
          bh[g] = *reinterpret_cast<const short8*>(Bh + base);
          bl[g] = *reinterpret_cast<const short8*>(Bl + base);
        }
        // per-acc pass order hh, lh, hl (bit-identical to r2/r4)
#pragma unroll
        for (int g = 0; g < 3; ++g) {
          acc[0][t][g] = MFMA(ah0, bh[g], acc[0][t][g]);
          acc[1][t][g] = MFMA(ah1, bh[g], acc[1][t][g]);
        }
#pragma unroll
        for (int g = 0; g < 3; ++g) {
          acc[0][t][g] = MFMA(al0, bh[g], acc[0][t][g]);
          acc[1][t][g] = MFMA(al1, bh[g], acc[1][t][g]);
        }
#pragma unroll
        for (int g = 0; g < 3; ++g) {
          acc[0][t][g] = MFMA(ah0, bl[g], acc[0][t][g]);
          acc[1][t][g] = MFMA(ah1, bl[g], acc[1][t][g]);
        }
      }
    }
    __builtin_amdgcn_s_setprio(0);
  };

  // ---- gate phase: consume acc (same wave), update h exact, write A, osc ----
  auto gate_phase = [&]() {
    float wr[2], wz[2], wn[2], br[2], bz[2], bn[2], wo[2];
#pragma unroll
    for (int t = 0; t < 2; ++t) {
      const int j = gwv * 32 + t * 16 + c16;
      wr[t] = prm[0][j]; wz[t] = prm[1][j]; wn[t] = prm[2][j];
      br[t] = prm[3][j]; bz[t] = prm[4][j]; bn[t] = prm[5][j];
      wo[t] = prm[9][j];
    }
    float opart[2][4];
#pragma unroll
    for (int m = 0; m < 2; ++m) {
#pragma unroll
      for (int r = 0; r < 4; ++r) {
        const int rl = m * 16 + grp * 4 + r;
        const float x = __shfl(xqr, rl);
#pragma unroll
        for (int t = 0; t < 2; ++t) {
          const int j = gwv * 32 + t * 16 + c16;
          const float ghr = acc[m][t][0][r];
          const float ghz = acc[m][t][1][r];
          const float ghn = acc[m][t][2][r];
          const float gr = fmaf(x, wr[t], br[t]) + ghr;   // r4 exact exprs
          const float gz = fmaf(x, wz[t], bz[t]) + ghz;
          const float gni = fmaf(x, wn[t], bn[t]);
          const float rg = 1.0f / (1.0f + __expf(-gr));
          const float zg = 1.0f / (1.0f + __expf(-gz));
          const float ta = gni + rg * ghn;
          const float at = fabsf(ta);
          const float et = __expf(-2.0f * at);
          const float th = copysignf((1.0f - et) / (1.0f + et), ta);
          const float hn = fmaf(zg, h_reg[m][r][t] - th, th);
          if (t == 0) opart[m][r] = hn * wo[0];
          else opart[m][r] = fmaf(hn, wo[1], opart[m][r]);
          const float hnext = hn + emb[(size_t)(row0 + rl) * kH + j];
          h_reg[m][r][t] = hnext;
          short hh, hl;
          bsplit(hnext, hh, hl);
          Ah[gid][rl][j] = hh;
          Al[gid][rl][j] = hl;
        }
#pragma unroll
        for (int mask = 1; mask < 16; mask <<= 1)
          opart[m][r] += __shfl_xor(opart[m][r], mask, 16);
      }
    }
    if (c16 == 0) {
#pragma unroll
      for (int m = 0; m < 2; ++m)
#pragma unroll
        for (int r = 0; r < 4; ++r)
          osc[gid][m * 16 + grp * 4 + r][gwv] = opart[m][r];
    }
  };

  // ---- finalize o/q for the group's 32 rows (redundant across its waves) ----
  auto fin = [&](const int step) {
    const int row = lane & 31;
    const f32x4 s0 = *reinterpret_cast<const f32x4*>(&osc[gid][row][0]);
    const f32x4 s1 = *reinterpret_cast<const f32x4*>(&osc[gid][row][4]);
    float s = bo;
    s += s0[0]; s += s0[1]; s += s0[2]; s += s0[3];
    s += s1[0]; s += s1[1]; s += s1[2]; s += s1[3];
    const float q = s > 0.0f ? 1.0f : -1.0f;
    if (lane < 32) {
      xqr = q;
      if (gwv == 0) {
        const size_t gr = (size_t)(row0 + row);
        out[gr * kNOut + step] = s;
        out[q_off + gr * kNOut + step] = q;
      }
    }
  };

  // ---- phase-offset main loop: every phase = one group MFMA + one group gates
  for (int k = 0; k < kNOut; ++k) {
    if (gid == 0) { if (k > 0) fin(k - 1); mfma_phase(); }
    else          { if (k > 0) gate_phase(); }
    __syncthreads();
    if (gid == 0) { gate_phase(); }
    else          { if (k > 0) fin(k - 1); mfma_phase(); }
    __syncthreads();
  }
  if (gid == 0) { fin(kNOut - 1); }
  else          { gate_phase(); }
  __syncthreads();
  if (gid == 1) { fin(kNOut - 1); }
}

extern "C" void kernel_launch(void* const* d_in, const int* in_sizes, int n_in,
                              void* d_out, int out_size, void* d_ws, size_t ws_size,
                              hipStream_t stream) {
  (void)in_sizes; (void)n_in; (void)out_size; (void)ws_size;
  const float* emb = (const float*)d_in[0];
  const float* w_ih = (const float*)d_in[1];
  const float* w_hh = (const float*)d_in[2];
  const float* b_ih = (const float*)d_in[3];
  const float* b_hh = (const float*)d_in[4];
  const float* w_out = (const float*)d_in[5];
  const float* b_out = (const float*)d_in[6];

  short* Bh = (short*)d_ws;                  // [768][256] bf16 hi
  short* Bl = Bh + kWhh;                     // [768][256] bf16 lo (768 KiB total)

  split_whh_kernel<<<kWhh / (256 * 4), 256, 0, stream>>>(w_hh, Bh, Bl);
  rbq_pp_kernel<<<kBL / 64, kThreads, 0, stream>>>(
      emb, w_ih, b_ih, b_hh, w_out, b_out, Bh, Bl, (float*)d_out);
}